// Round 11
// baseline (150.741 us; speedup 1.0000x reference)
//
#include <hip/hip_runtime.h>
#include <hip/hip_cooperative_groups.h>

namespace cg = cooperative_groups;

// PathBundleChoiceScorer — reduced computation (verified rounds 1-10):
//   t1 = tanh(x @ W1^T); t2 = tanh(t1 @ W2^T); s[n] = dot(t2[n,:], Wout)
//   out[n] = top9-weighted collapse of {c_j*s}, c fixed {-1,0,+1} pattern.
// Round 11: fuse cvt -> GEMM1 -> GEMM2 -> finalize into ONE cooperative
// kernel (grid 256x256, 3x grid.sync()). Timeline showed ~16us of the 56us
// was inter-launch gaps; phase bodies are the round-4 kernels VERBATIM.

typedef __attribute__((ext_vector_type(4))) float     f32x4;
typedef __attribute__((ext_vector_type(8))) _Float16  f16x8;

#define AS1 __attribute__((address_space(1)))
#define AS3 __attribute__((address_space(3)))
#define GLOAD16(gp, lp) \
    __builtin_amdgcn_global_load_lds((AS1 const void*)(gp), (AS3 void*)(lp), 16, 0, 0)

// ---- GEMM phase (round-4 body): C = A @ B^T, 128x128 tile, 4 waves --------
// EPI=0: Cout = tanh(acc) f16.  EPI=1: s_part = fused wout dot partials.
template<int EPI>
__device__ __forceinline__
void gemm_phase(char* sm, const _Float16* __restrict__ A,
                const _Float16* __restrict__ B, _Float16* __restrict__ Cout,
                const float* __restrict__ wout, float* __restrict__ s_part)
{
    const int tid  = threadIdx.x;
    const int lane = tid & 63;
    const int wid  = tid >> 6;
    const int wm   = wid >> 1;
    const int wn   = wid & 1;
    const int l15  = lane & 15;
    const int g    = lane >> 4;       // k-group 0..3

    // bijective XCD swizzle: XCD (= blk%8) owns a contiguous bm-stripe
    const int b  = blockIdx.x;                     // 0..255
    const int bm = (b & 7) * 4 + ((b >> 3) & 3);   // 0..31
    const int bn = b >> 5;                         // 0..7

    // staging: 32 chunks of 1KB (16 A + 16 B), 8 per wave; linear LDS dest,
    // pre-swizzled global source (slot s holds k-group s^(row&7)).
    const char* aS[4]; const char* bS[4]; int aD[4], bD[4];
#pragma unroll
    for (int j = 0; j < 4; ++j) {
        const int c = wid * 4 + j;
        const int r = c * 8 + (lane >> 3), s = lane & 7;
        aS[j] = (const char*)A + (size_t)(bm * 128 + r) * 2048 + 16 * (s ^ (r & 7));
        aD[j] = c * 1024;
        bS[j] = (const char*)B + (size_t)(bn * 128 + r) * 2048 + 16 * (s ^ (r & 7));
        bD[j] = 16384 + c * 1024;
    }

    int aoff[4][2], boff[4][2];
#pragma unroll
    for (int f = 0; f < 4; ++f) {
        const int ra = wm * 64 + f * 16 + l15;
        const int rb = wn * 64 + f * 16 + l15;
#pragma unroll
        for (int kh = 0; kh < 2; ++kh) {
            aoff[f][kh] = ra * 128 + 16 * (((kh << 2) | g) ^ (ra & 7));
            boff[f][kh] = 16384 + rb * 128 + 16 * (((kh << 2) | g) ^ (rb & 7));
        }
    }

    f32x4 acc[4][4];
#pragma unroll
    for (int i = 0; i < 4; ++i)
#pragma unroll
        for (int j = 0; j < 4; ++j) acc[i][j] = (f32x4)0.f;

#define STAGE(buf, kt) do {                                      \
        const int _ko = (kt) * 128;                              \
        char* _D = sm + (buf) * 32768;                           \
        _Pragma("unroll")                                        \
        for (int _j = 0; _j < 4; ++_j) {                         \
            GLOAD16(aS[_j] + _ko, _D + aD[_j]);                  \
            GLOAD16(bS[_j] + _ko, _D + bD[_j]);                  \
        }                                                        \
    } while (0)

#define COMPUTE(buf) do {                                                        \
        const char* _L = sm + (buf) * 32768;                                     \
        _Pragma("unroll")                                                        \
        for (int _kh = 0; _kh < 2; ++_kh) {                                      \
            f16x8 _a[4], _b[4];                                                  \
            _Pragma("unroll")                                                    \
            for (int _f = 0; _f < 4; ++_f) {                                     \
                _a[_f] = *(const f16x8*)(_L + aoff[_f][_kh]);                    \
                _b[_f] = *(const f16x8*)(_L + boff[_f][_kh]);                    \
            }                                                                    \
            _Pragma("unroll")                                                    \
            for (int _mf = 0; _mf < 4; ++_mf)                                    \
            _Pragma("unroll")                                                    \
            for (int _nf = 0; _nf < 4; ++_nf)                                    \
                acc[_mf][_nf] = __builtin_amdgcn_mfma_f32_16x16x32_f16(          \
                    _a[_mf], _b[_nf], acc[_mf][_nf], 0, 0, 0);                   \
        }                                                                        \
    } while (0)

    STAGE(0, 0);
    STAGE(1, 1);
#pragma unroll 1
    for (int t = 0; t < 15; ++t) {
        asm volatile("s_waitcnt vmcnt(8)" ::: "memory");  // k-tile t landed
        __builtin_amdgcn_s_barrier();
        __builtin_amdgcn_sched_barrier(0);
        COMPUTE(t & 1);
        asm volatile("s_waitcnt lgkmcnt(0)" ::: "memory");
        __builtin_amdgcn_sched_barrier(0);
        __builtin_amdgcn_s_barrier();                     // all reads of buf done
        if (t < 14) STAGE(t & 1, t + 2);
    }
    asm volatile("s_waitcnt vmcnt(0)" ::: "memory");
    __builtin_amdgcn_s_barrier();
    __builtin_amdgcn_sched_barrier(0);
    COMPUTE(1);   // t = 15

    if (EPI == 0) {
#pragma unroll
        for (int mf = 0; mf < 4; ++mf)
#pragma unroll
        for (int nf = 0; nf < 4; ++nf)
#pragma unroll
        for (int jj = 0; jj < 4; ++jj) {
            const int row = bm * 128 + wm * 64 + mf * 16 + g * 4 + jj;
            const int col = bn * 128 + wn * 64 + nf * 16 + l15;
            Cout[(size_t)row * 1024 + col] = (_Float16)tanhf(acc[mf][nf][jj]);
        }
    } else {
        float w[4];
#pragma unroll
        for (int nf = 0; nf < 4; ++nf)
            w[nf] = wout[bn * 128 + wn * 64 + nf * 16 + l15];
#pragma unroll
        for (int mf = 0; mf < 4; ++mf)
#pragma unroll
        for (int jj = 0; jj < 4; ++jj) {
            float v = 0.f;
#pragma unroll
            for (int nf = 0; nf < 4; ++nf)
                v += tanhf(acc[mf][nf][jj]) * w[nf];
            v += __shfl_xor(v, 1, 64);
            v += __shfl_xor(v, 2, 64);
            v += __shfl_xor(v, 4, 64);
            v += __shfl_xor(v, 8, 64);
            if (l15 == 0) {
                const int row = bm * 128 + wm * 64 + mf * 16 + g * 4 + jj;
                s_part[row * 16 + bn * 2 + wn] = v;
            }
        }
    }
#undef STAGE
#undef COMPUTE
}

// ---- fused cooperative kernel ----------------------------------------------
__global__ __launch_bounds__(256, 2)
void pbcs_fused(const float* __restrict__ x,  _Float16* __restrict__ xf,
                const float* __restrict__ w1, _Float16* __restrict__ w1f,
                const float* __restrict__ w2, _Float16* __restrict__ w2f,
                const float* __restrict__ wout, _Float16* __restrict__ t1f,
                float* __restrict__ s_part,
                const float* __restrict__ soa_w, const float* __restrict__ soa_b,
                const float* __restrict__ sob_w, const float* __restrict__ sob_b,
                float* __restrict__ out)
{
    __shared__ char smem[2][32768];
    cg::grid_group grid = cg::this_grid();

    // ---- phase 0: f32 -> f16 convert (x 4M, W1 1M, W2 1M; 8 elems/thread) --
#pragma unroll 1
    for (int it = 0; it < 12; ++it) {
        const int vb = blockIdx.x + it * 256;      // virtual block 0..3071
        const float* src; _Float16* dst; int idx;
        if (vb < 2048)      { src = x;  dst = xf;  idx = vb * 256 + threadIdx.x; }
        else if (vb < 2560) { src = w1; dst = w1f; idx = (vb - 2048) * 256 + threadIdx.x; }
        else                { src = w2; dst = w2f; idx = (vb - 2560) * 256 + threadIdx.x; }
        const float4 v0 = ((const float4*)src)[idx * 2];
        const float4 v1 = ((const float4*)src)[idx * 2 + 1];
        f16x8 h;
        h[0] = (_Float16)v0.x; h[1] = (_Float16)v0.y;
        h[2] = (_Float16)v0.z; h[3] = (_Float16)v0.w;
        h[4] = (_Float16)v1.x; h[5] = (_Float16)v1.y;
        h[6] = (_Float16)v1.z; h[7] = (_Float16)v1.w;
        ((f16x8*)dst)[idx] = h;
    }
    grid.sync();

    // ---- phase 1: t1 = tanh(xf @ W1^T) ----
    gemm_phase<0>(&smem[0][0], xf, w1f, t1f, nullptr, nullptr);
    grid.sync();

    // ---- phase 2: s_part = fused wout dot of tanh(t1f @ W2^T) ----
    gemm_phase<1>(&smem[0][0], t1f, w2f, nullptr, wout, s_part);
    grid.sync();

    // ---- phase 3: finalize (4 rows per wave; 1024 waves) ----
    const int lane = threadIdx.x & 63;
    const int gw   = blockIdx.x * 4 + (threadIdx.x >> 6);   // 0..1023
#pragma unroll 1
    for (int rr = 0; rr < 4; ++rr) {
        const int row = gw * 4 + rr;

        float part = (lane < 16) ? s_part[row * 16 + lane] : 0.f;
#pragma unroll
        for (int off = 32; off > 0; off >>= 1) part += __shfl_xor(part, off, 64);
        const float s = part;

        const float C7 = 0.8975979010256552f;   // 2*pi/7
        float tS = 0.f, tZ = 0.f, tN = 0.f;
        if (lane < 32) {
            const float aw = soa_w[lane];
            const float ab = soa_b[lane];
            const float bw = sob_w[lane];
            tS = bw * sinf(C7 * fmaf(aw,  s, ab));
            tZ = bw * sinf(C7 * ab);
            tN = bw * sinf(C7 * fmaf(aw, -s, ab));
        }
#pragma unroll
        for (int off = 32; off > 0; off >>= 1) {
            tS += __shfl_xor(tS, off, 64);
            tZ += __shfl_xor(tZ, off, 64);
            tN += __shfl_xor(tN, off, 64);
        }
        const float bb = sob_b[0];
        const float fS = tS + bb;
        const float f0 = tZ + bb;
        const float fN = tN + bb;

        // 27 paths: P[k] = {1,0,-1,0,0,0,-1,0,1}; tri q: (-pos, 0, +pos)
        const int j  = lane;
        const int kk = j / 3;
        const int q  = j - kk * 3;
        const int p  = ((0x101 >> kk) & 1) - ((0x044 >> kk) & 1);
        const int c  = (q == 0) ? -p : ((q == 2) ? p : 0);
        const float val = (float)c * s;
        const float sc  = (c == 0) ? f0 : ((c > 0) ? fS : fN);

        int rank = 0;
#pragma unroll 1
        for (int i = 0; i < 27; ++i) {
            const float sci = __shfl(sc, i, 64);
            rank += (sci > sc) || (sci == sc && i < j);
        }
        const float mx = fmaxf(fS, fmaxf(f0, fN));
        float e = (j < 27 && rank < 9) ? expf(sc - mx) : 0.f;
        float num = val * e;
        float den = e;
#pragma unroll
        for (int off = 32; off > 0; off >>= 1) {
            num += __shfl_xor(num, off, 64);
            den += __shfl_xor(den, off, 64);
        }
        if (lane == 0) out[row] = num / den;
    }
}

extern "C" void kernel_launch(void* const* d_in, const int* in_sizes, int n_in,
                              void* d_out, int out_size, void* d_ws, size_t ws_size,
                              hipStream_t stream)
{
    const float* x     = (const float*)d_in[0];
    const float* W1    = (const float*)d_in[1];
    const float* W2    = (const float*)d_in[2];
    const float* Wout  = (const float*)d_in[3];
    const float* soa_w = (const float*)d_in[12];
    const float* soa_b = (const float*)d_in[13];
    const float* sob_w = (const float*)d_in[14];
    const float* sob_b = (const float*)d_in[15];

    char* ws = (char*)d_ws;
    _Float16* xf  = (_Float16*)ws;                    //  8MB  [4096,1024]
    _Float16* t1f = (_Float16*)(ws + (8u  << 20));    //  8MB  [4096,1024]
    _Float16* w1f = (_Float16*)(ws + (16u << 20));    //  2MB  [1024,1024]
    _Float16* w2f = (_Float16*)(ws + (18u << 20));    //  2MB  [1024,1024]
    float* s_part = (float*)(ws + (20u << 20));       //  256KB
    float* outp   = (float*)d_out;

    void* args[] = {
        (void*)&x,  (void*)&xf,  (void*)&W1, (void*)&w1f,
        (void*)&W2, (void*)&w2f, (void*)&Wout, (void*)&t1f,
        (void*)&s_part,
        (void*)&soa_w, (void*)&soa_b, (void*)&sob_w, (void*)&sob_b,
        (void*)&outp
    };
    hipLaunchCooperativeKernel((const void*)pbcs_fused, dim3(256), dim3(256),
                               args, 0, stream);
}

// Round 12
// 56.152 us; speedup vs baseline: 2.6845x; 2.6845x over previous
//
#include <hip/hip_runtime.h>

// PathBundleChoiceScorer — reduced computation (verified rounds 1-11):
//   t1 = tanh(x @ W1^T); t2 = tanh(t1 @ W2^T); s[n] = dot(t2[n,:], Wout)
//   out[n] = top9-weighted collapse of {c_j*s}, c fixed {-1,0,+1} pattern.
// Round 12: restore the round-4/round-10 configuration (proven 56.2-56.4us).
// fp16 single-product MFMA GEMMs, 128x128 tile, 4 waves, BK=64, dbuf LDS,
// counted vmcnt(8), 8-slot XOR swizzle, XCD-bijective block swizzle.
// Experiment record: byte-cuts won (R2,R4); conflicts-fix hidden (R3);
// TLP/split-K null (R5,R6); deeper pipeline regress (R7); f32-staging
// regress (R8); cross-block split-K invalid (R9); cooperative fusion 2.7x
// regress (R11 - grid.sync is expensive on gfx950). This is the plateau.

typedef __attribute__((ext_vector_type(4))) float     f32x4;
typedef __attribute__((ext_vector_type(8))) _Float16  f16x8;

#define AS1 __attribute__((address_space(1)))
#define AS3 __attribute__((address_space(3)))
#define GLOAD16(gp, lp) \
    __builtin_amdgcn_global_load_lds((AS1 const void*)(gp), (AS3 void*)(lp), 16, 0, 0)

// ---- f32 -> f16 convert: x (4M elems), W1 (1M), W2 (1M); 8 elems/thread ----
__global__ __launch_bounds__(256)
void pbcs_cvt(const float* __restrict__ x,  _Float16* __restrict__ xo,
              const float* __restrict__ w1, _Float16* __restrict__ w1o,
              const float* __restrict__ w2, _Float16* __restrict__ w2o)
{
    const int b = blockIdx.x;
    const float* src; _Float16* dst; int idx;
    if (b < 2048)      { src = x;  dst = xo;  idx = b * 256 + threadIdx.x; }
    else if (b < 2560) { src = w1; dst = w1o; idx = (b - 2048) * 256 + threadIdx.x; }
    else               { src = w2; dst = w2o; idx = (b - 2560) * 256 + threadIdx.x; }
    const float4 v0 = ((const float4*)src)[idx * 2];
    const float4 v1 = ((const float4*)src)[idx * 2 + 1];
    f16x8 h;
    h[0] = (_Float16)v0.x; h[1] = (_Float16)v0.y;
    h[2] = (_Float16)v0.z; h[3] = (_Float16)v0.w;
    h[4] = (_Float16)v1.x; h[5] = (_Float16)v1.y;
    h[6] = (_Float16)v1.z; h[7] = (_Float16)v1.w;
    ((f16x8*)dst)[idx] = h;
}

// ---- fp16 MFMA GEMM:  C = A @ B^T, A [4096,1024] f16, B [1024,1024] f16 ----
// 256 threads = 4 waves (2m x 2n), wave tile 64x64, BK=64, 16 k-tiles.
// EPI=0: Cout = tanh(acc) as f16.  EPI=1: s_part += fused wout dot.
template<int EPI>
__global__ __launch_bounds__(256, 2)
void pbcs_gemm16(const _Float16* __restrict__ A, const _Float16* __restrict__ B,
                 _Float16* __restrict__ Cout, const float* __restrict__ wout,
                 float* __restrict__ s_part)
{
    __shared__ char smem[2][32768];   // [buf][ A 16K | B 16K ]

    const int tid  = threadIdx.x;
    const int lane = tid & 63;
    const int wid  = tid >> 6;
    const int wm   = wid >> 1;
    const int wn   = wid & 1;
    const int l15  = lane & 15;
    const int g    = lane >> 4;       // k-group 0..3

    // bijective XCD swizzle: XCD (= blk%8) owns a contiguous bm-stripe
    const int b  = blockIdx.x;                     // 0..255
    const int bm = (b & 7) * 4 + ((b >> 3) & 3);   // 0..31
    const int bn = b >> 5;                         // 0..7

    // ---- staging: 32 chunks of 1KB (16 A + 16 B), 8 per wave ----
    // chunk c covers rows c*8..c*8+7 (128B/row = 64 f16); linear LDS dest,
    // pre-swizzled global source (slot s holds k-group s^(row&7)).
    const char* aS[4]; const char* bS[4]; int aD[4], bD[4];
#pragma unroll
    for (int j = 0; j < 4; ++j) {
        const int c = wid * 4 + j;
        const int r = c * 8 + (lane >> 3), s = lane & 7;
        aS[j] = (const char*)A + (size_t)(bm * 128 + r) * 2048 + 16 * (s ^ (r & 7));
        aD[j] = c * 1024;
        bS[j] = (const char*)B + (size_t)(bn * 128 + r) * 2048 + 16 * (s ^ (r & 7));
        bD[j] = 16384 + c * 1024;
    }

    // ---- LDS read offsets (swizzled) ----
    int aoff[4][2], boff[4][2];
#pragma unroll
    for (int f = 0; f < 4; ++f) {
        const int ra = wm * 64 + f * 16 + l15;
        const int rb = wn * 64 + f * 16 + l15;
#pragma unroll
        for (int kh = 0; kh < 2; ++kh) {
            aoff[f][kh] = ra * 128 + 16 * (((kh << 2) | g) ^ (ra & 7));
            boff[f][kh] = 16384 + rb * 128 + 16 * (((kh << 2) | g) ^ (rb & 7));
        }
    }

    f32x4 acc[4][4];
#pragma unroll
    for (int i = 0; i < 4; ++i)
#pragma unroll
        for (int j = 0; j < 4; ++j) acc[i][j] = (f32x4)0.f;

#define STAGE(buf, kt) do {                                      \
        const int _ko = (kt) * 128;                              \
        _Pragma("unroll")                                        \
        for (int _j = 0; _j < 4; ++_j) {                         \
            GLOAD16(aS[_j] + _ko, smem[buf] + aD[_j]);           \
            GLOAD16(bS[_j] + _ko, smem[buf] + bD[_j]);           \
        }                                                        \
    } while (0)

#define COMPUTE(buf) do {                                                        \
        _Pragma("unroll")                                                        \
        for (int _kh = 0; _kh < 2; ++_kh) {                                      \
            f16x8 _a[4], _b[4];                                                  \
            _Pragma("unroll")                                                    \
            for (int _f = 0; _f < 4; ++_f) {                                     \
                _a[_f] = *(const f16x8*)(smem[buf] + aoff[_f][_kh]);             \
                _b[_f] = *(const f16x8*)(smem[buf] + boff[_f][_kh]);             \
            }                                                                    \
            _Pragma("unroll")                                                    \
            for (int _mf = 0; _mf < 4; ++_mf)                                    \
            _Pragma("unroll")                                                    \
            for (int _nf = 0; _nf < 4; ++_nf)                                    \
                acc[_mf][_nf] = __builtin_amdgcn_mfma_f32_16x16x32_f16(          \
                    _a[_mf], _b[_nf], acc[_mf][_nf], 0, 0, 0);                   \
        }                                                                        \
    } while (0)

    // ---- double-buffered counted-vmcnt loop over 16 k-tiles ----
    STAGE(0, 0);
    STAGE(1, 1);
#pragma unroll 1
    for (int t = 0; t < 15; ++t) {
        asm volatile("s_waitcnt vmcnt(8)" ::: "memory");  // k-tile t landed
        __builtin_amdgcn_s_barrier();
        __builtin_amdgcn_sched_barrier(0);
        COMPUTE(t & 1);
        asm volatile("s_waitcnt lgkmcnt(0)" ::: "memory");
        __builtin_amdgcn_sched_barrier(0);
        __builtin_amdgcn_s_barrier();                     // all reads of buf done
        if (t < 14) STAGE(t & 1, t + 2);
    }
    asm volatile("s_waitcnt vmcnt(0)" ::: "memory");
    __builtin_amdgcn_s_barrier();
    __builtin_amdgcn_sched_barrier(0);
    COMPUTE(1);   // t = 15

    // ---- epilogue ----
    if (EPI == 0) {
#pragma unroll
        for (int mf = 0; mf < 4; ++mf)
#pragma unroll
        for (int nf = 0; nf < 4; ++nf)
#pragma unroll
        for (int jj = 0; jj < 4; ++jj) {
            const int row = bm * 128 + wm * 64 + mf * 16 + g * 4 + jj;
            const int col = bn * 128 + wn * 64 + nf * 16 + l15;
            Cout[(size_t)row * 1024 + col] = (_Float16)tanhf(acc[mf][nf][jj]);
        }
    } else {
        float w[4];
#pragma unroll
        for (int nf = 0; nf < 4; ++nf)
            w[nf] = wout[bn * 128 + wn * 64 + nf * 16 + l15];
#pragma unroll
        for (int mf = 0; mf < 4; ++mf)
#pragma unroll
        for (int jj = 0; jj < 4; ++jj) {
            float v = 0.f;
#pragma unroll
            for (int nf = 0; nf < 4; ++nf)
                v += tanhf(acc[mf][nf][jj]) * w[nf];
            v += __shfl_xor(v, 1, 64);
            v += __shfl_xor(v, 2, 64);
            v += __shfl_xor(v, 4, 64);
            v += __shfl_xor(v, 8, 64);
            if (l15 == 0) {
                const int row = bm * 128 + wm * 64 + mf * 16 + g * 4 + jj;
                s_part[row * 16 + bn * 2 + wn] = v;
            }
        }
    }
#undef STAGE
#undef COMPUTE
}

// ---- finalize: s = sum(s_part), then faithful 27-path top-9 collapse -------
__global__ __launch_bounds__(256)
void pbcs_finalize(const float* __restrict__ s_part,
                   const float* __restrict__ soa_w, const float* __restrict__ soa_b,
                   const float* __restrict__ sob_w, const float* __restrict__ sob_b,
                   float* __restrict__ out, int Nrows)
{
    const int row  = blockIdx.x * 4 + (threadIdx.x >> 6);
    const int lane = threadIdx.x & 63;
    if (row >= Nrows) return;

    float part = (lane < 16) ? s_part[row * 16 + lane] : 0.f;
#pragma unroll
    for (int off = 32; off > 0; off >>= 1) part += __shfl_xor(part, off, 64);
    const float s = part;

    const float C7 = 0.8975979010256552f;   // 2*pi/7
    float tS = 0.f, tZ = 0.f, tN = 0.f;
    if (lane < 32) {
        const float aw = soa_w[lane];
        const float ab = soa_b[lane];
        const float bw = sob_w[lane];
        tS = bw * sinf(C7 * fmaf(aw,  s, ab));
        tZ = bw * sinf(C7 * ab);
        tN = bw * sinf(C7 * fmaf(aw, -s, ab));
    }
#pragma unroll
    for (int off = 32; off > 0; off >>= 1) {
        tS += __shfl_xor(tS, off, 64);
        tZ += __shfl_xor(tZ, off, 64);
        tN += __shfl_xor(tN, off, 64);
    }
    const float bb = sob_b[0];
    const float fS = tS + bb;
    const float f0 = tZ + bb;
    const float fN = tN + bb;

    // 27 paths: P[k] = {1,0,-1,0,0,0,-1,0,1}; tri q: (-pos, 0, +pos)
    const int j  = lane;
    const int kk = j / 3;
    const int q  = j - kk * 3;
    const int p  = ((0x101 >> kk) & 1) - ((0x044 >> kk) & 1);
    const int c  = (q == 0) ? -p : ((q == 2) ? p : 0);
    const float val = (float)c * s;
    const float sc  = (c == 0) ? f0 : ((c > 0) ? fS : fN);

    int rank = 0;
#pragma unroll 1
    for (int i = 0; i < 27; ++i) {
        const float sci = __shfl(sc, i, 64);
        rank += (sci > sc) || (sci == sc && i < j);
    }
    const float mx = fmaxf(fS, fmaxf(f0, fN));
    float e = (j < 27 && rank < 9) ? expf(sc - mx) : 0.f;
    float num = val * e;
    float den = e;
#pragma unroll
    for (int off = 32; off > 0; off >>= 1) {
        num += __shfl_xor(num, off, 64);
        den += __shfl_xor(den, off, 64);
    }
    if (lane == 0) out[row] = num / den;
}

extern "C" void kernel_launch(void* const* d_in, const int* in_sizes, int n_in,
                              void* d_out, int out_size, void* d_ws, size_t ws_size,
                              hipStream_t stream)
{
    const float* x     = (const float*)d_in[0];
    const float* W1    = (const float*)d_in[1];
    const float* W2    = (const float*)d_in[2];
    const float* Wout  = (const float*)d_in[3];
    const float* soa_w = (const float*)d_in[12];
    const float* soa_b = (const float*)d_in[13];
    const float* sob_w = (const float*)d_in[14];
    const float* sob_b = (const float*)d_in[15];

    const int Nr = 4096;
    char* ws = (char*)d_ws;
    _Float16* xf  = (_Float16*)ws;                    //  8MB  [4096,1024]
    _Float16* t1f = (_Float16*)(ws + (8u  << 20));    //  8MB  [4096,1024]
    _Float16* w1f = (_Float16*)(ws + (16u << 20));    //  2MB  [1024,1024]
    _Float16* w2f = (_Float16*)(ws + (18u << 20));    //  2MB  [1024,1024]
    float* s_part = (float*)(ws + (20u << 20));       //  256KB

    pbcs_cvt<<<3072, 256, 0, stream>>>(x, xf, W1, w1f, W2, w2f);

    pbcs_gemm16<0><<<256, 256, 0, stream>>>(xf,  w1f, t1f, nullptr, nullptr);
    pbcs_gemm16<1><<<256, 256, 0, stream>>>(t1f, w2f, nullptr, Wout, s_part);

    pbcs_finalize<<<Nr / 4, 256, 0, stream>>>(s_part, soa_w, soa_b, sob_w, sob_b,
                                              (float*)d_out, Nr);
}